// Round 8
// baseline (28.438 us; speedup 1.0000x reference)
//
#include <hip/hip_runtime.h>
#include <hip/hip_fp16.h>
#include <math.h>

constexpr int B    = 512;
constexpr int NIN  = 1024;
constexpr int NK   = 128;
constexpr int DK   = 5;
constexpr int NF   = NK * DK;     // 640 flattened kernel columns
constexpr int NOUT = NIN + NK;    // 1152
constexpr int SPLITK = 8;         // K chunks (128 each)
constexpr int LDA = 136;          // LDS row stride in halves (128 + 8 pad)
#define LOG2E 1.44269504088896f

typedef _Float16 f16x2 __attribute__((ext_vector_type(2)));
typedef _Float16 f16x4 __attribute__((ext_vector_type(4)));
typedef _Float16 f16x8 __attribute__((ext_vector_type(8)));
typedef float    f32x4 __attribute__((ext_vector_type(4)));

union H2 { __half2 h; f16x2 v; unsigned u; };

// ---------------------------------------------------------------------------
// Kernel 1: split-K MFMA GEMM, SINGLE staging phase per block.
//   grid 640 = 80 tiles (10n x 8b) x 8 z; 256 thr = 4 waves (n-subtiles? no:
//   wave w owns n-sub w*16, all 64 b).  K-chunk = 128 (4 MFMA k-steps).
//   All 16 global float4 loads issued up-front; one barrier pair.
// ---------------------------------------------------------------------------
__global__ __launch_bounds__(256) void gemm_kernel(
        const float* __restrict__ x,       // [512][1024]
        const float* __restrict__ theta,   // [1024][640]
        float* __restrict__ actvP,         // [8][640][512]
        float* __restrict__ ps) {          // [8][640]
    __shared__ _Float16 Ath[64 * LDA];     // theta^T tile [n][k]
    __shared__ _Float16 Bxh[64 * LDA];     // x tile [b][k]
    __shared__ float    red2[16][64];

    const int t    = threadIdx.x;
    const int tile = blockIdx.x >> 3;
    const int z    = blockIdx.x & 7;
    const int n0   = (tile >> 3) * 64;
    const int b0   = (tile & 7) * 64;
    const bool do_ps = (tile & 7) == 0;
    const int kw   = z * 128;

    // ---- stage theta: thread (kq = t>>4, 4 n-cols) reads 8 k-rows ----
    const int kq  = t >> 4;            // 0..15 (8 k-rows each)
    const int tn4 = (t & 15) * 4;
    float4 tv[8];
    #pragma unroll
    for (int i = 0; i < 8; ++i)
        tv[i] = *(const float4*)&theta[(kw + kq * 8 + i) * NF + n0 + tn4];

    // ---- stage x: thread (br = t>>2, ki = t&3) reads 8 float4 along k ----
    const int br = t >> 2;             // 0..63
    const int ki = t & 3;
    float4 xv[8];
    #pragma unroll
    for (int i = 0; i < 8; ++i)
        xv[i] = *(const float4*)&x[(b0 + br) * NIN + kw + (ki + i * 4) * 4];

    // theta^2 partials from registers (b0==0 blocks only)
    if (do_ps) {
        float sq0 = 0.f, sq1 = 0.f, sq2 = 0.f, sq3 = 0.f;
        #pragma unroll
        for (int i = 0; i < 8; ++i) {
            sq0 += tv[i].x * tv[i].x;  sq1 += tv[i].y * tv[i].y;
            sq2 += tv[i].z * tv[i].z;  sq3 += tv[i].w * tv[i].w;
        }
        red2[kq][tn4 + 0] = sq0;  red2[kq][tn4 + 1] = sq1;
        red2[kq][tn4 + 2] = sq2;  red2[kq][tn4 + 3] = sq3;
    }

    // transpose theta regs -> Ath[n][k] (f16x8 along k, 2-way banks = free)
    {
        f16x8 h;
        #pragma unroll
        for (int i = 0; i < 8; ++i) h[i] = (_Float16)tv[i].x;
        *(f16x8*)&Ath[(tn4 + 0) * LDA + kq * 8] = h;
        #pragma unroll
        for (int i = 0; i < 8; ++i) h[i] = (_Float16)tv[i].y;
        *(f16x8*)&Ath[(tn4 + 1) * LDA + kq * 8] = h;
        #pragma unroll
        for (int i = 0; i < 8; ++i) h[i] = (_Float16)tv[i].z;
        *(f16x8*)&Ath[(tn4 + 2) * LDA + kq * 8] = h;
        #pragma unroll
        for (int i = 0; i < 8; ++i) h[i] = (_Float16)tv[i].w;
        *(f16x8*)&Ath[(tn4 + 3) * LDA + kq * 8] = h;
    }
    // x regs -> Bxh[b][k]
    #pragma unroll
    for (int i = 0; i < 8; ++i) {
        f16x4 h;
        h[0] = (_Float16)xv[i].x;  h[1] = (_Float16)xv[i].y;
        h[2] = (_Float16)xv[i].z;  h[3] = (_Float16)xv[i].w;
        *(f16x4*)&Bxh[br * LDA + (ki + i * 4) * 4] = h;
    }
    __syncthreads();

    // ---- MFMA: wave w owns n-sub = w*16; 4 b-subtiles x 4 k-steps ----
    const int w   = t >> 6;
    const int l   = t & 63;
    const int r16 = l & 15;
    const int kg  = l >> 4;

    f32x4 acc0 = {0.f,0.f,0.f,0.f}, acc1 = {0.f,0.f,0.f,0.f};
    f32x4 acc2 = {0.f,0.f,0.f,0.f}, acc3 = {0.f,0.f,0.f,0.f};
    #pragma unroll
    for (int ks = 0; ks < 4; ++ks) {
        const f16x8 av  = *(const f16x8*)&Ath[(w*16 + r16)*LDA + ks*32 + kg*8];
        const f16x8 bv0 = *(const f16x8*)&Bxh[( 0 + r16)*LDA + ks*32 + kg*8];
        const f16x8 bv1 = *(const f16x8*)&Bxh[(16 + r16)*LDA + ks*32 + kg*8];
        const f16x8 bv2 = *(const f16x8*)&Bxh[(32 + r16)*LDA + ks*32 + kg*8];
        const f16x8 bv3 = *(const f16x8*)&Bxh[(48 + r16)*LDA + ks*32 + kg*8];
        acc0 = __builtin_amdgcn_mfma_f32_16x16x32_f16(av, bv0, acc0, 0, 0, 0);
        acc1 = __builtin_amdgcn_mfma_f32_16x16x32_f16(av, bv1, acc1, 0, 0, 0);
        acc2 = __builtin_amdgcn_mfma_f32_16x16x32_f16(av, bv2, acc2, 0, 0, 0);
        acc3 = __builtin_amdgcn_mfma_f32_16x16x32_f16(av, bv3, acc3, 0, 0, 0);
    }

    // store partials: C map col=lane&15, row=(lane>>4)*4+reg [m89/m91]
    {
        float* dst = actvP + (size_t)z * NF * B
                   + (size_t)(n0 + w*16 + kg*4) * B + b0 + r16;
        #pragma unroll
        for (int j = 0; j < 4; ++j) {
            dst[j*B +  0] = acc0[j];
            dst[j*B + 16] = acc1[j];
            dst[j*B + 32] = acc2[j];
            dst[j*B + 48] = acc3[j];
        }
    }
    if (do_ps) {
        __syncthreads();
        if (t < 64) {
            float tot = 0.f;
            #pragma unroll
            for (int rr = 0; rr < 16; ++rr) tot += red2[rr][t];
            ps[z * NF + n0 + t] = tot;
        }
    }
}

// ---------------------------------------------------------------------------
// Kernel 2: split-K reduce + scale -> f16.
//   actv16[n][b] = f16( (sum_z actvP[z][n][b]) * exp(lws[n])*rsqrt(sum ps)*log2e )
// grid 320 x 256: block = 2 n-rows, thread = (row half, 4 b-cols).
// ---------------------------------------------------------------------------
__global__ __launch_bounds__(256) void rs_kernel(
        const float* __restrict__ actvP,   // [8][640][512]
        const float* __restrict__ ps,      // [8][640]
        const float* __restrict__ lws,     // [640]
        __half* __restrict__ actv16) {     // [640][512]
    const int t   = threadIdx.x;
    const int row = blockIdx.x * 2 + (t >> 7);
    const int c4  = (t & 127) * 4;

    float nrm = 0.f;
    #pragma unroll
    for (int zz = 0; zz < SPLITK; ++zz) nrm += ps[zz * NF + row];
    const float s = __expf(lws[row]) * rsqrtf(nrm) * LOG2E;

    const float* p = actvP + (size_t)row * B + c4;
    float4 vs = *(const float4*)(p);
    #pragma unroll
    for (int zz = 1; zz < SPLITK; ++zz) {
        const float4 v = *(const float4*)(p + (size_t)zz * NF * B);
        vs.x += v.x; vs.y += v.y; vs.z += v.z; vs.w += v.w;
    }
    f16x4 h;
    h[0] = (_Float16)(vs.x * s);
    h[1] = (_Float16)(vs.y * s);
    h[2] = (_Float16)(vs.z * s);
    h[3] = (_Float16)(vs.w * s);
    *(f16x4*)&actv16[(size_t)row * B + c4] = h;
}

// ---------------------------------------------------------------------------
// Kernel 3: pairwise finish, packed f16 (unchanged from R7).
// grid (128 k, 8 e) = 1024 blocks, 256 thr.
// ---------------------------------------------------------------------------
__global__ __launch_bounds__(256) void pairwise_kernel(
        const __half* __restrict__ actv16, // [640][512]
        const float* __restrict__ bias,    // [128]
        const float* __restrict__ x,       // [512][1024]
        float* __restrict__ out) {         // [512][1152]
    __shared__ __half a16s[DK * B];        // 5120 B
    __shared__ float  red[8 * 64];

    const int k = blockIdx.x;
    const int e = blockIdx.y;
    const int t = threadIdx.x;

    if (e < 4) {
        const int row = k * 4 + e;
        ((float4*)out)[row * (NOUT/4) + t] = ((const float4*)x)[row * (NIN/4) + t];
    }

    {
        const uint4* src = (const uint4*)(actv16 + (size_t)k * DK * B);
        ((uint4*)a16s)[t] = src[t];
        if (t < 64) ((uint4*)a16s)[256 + t] = src[256 + t];
    }
    __syncthreads();

    const int g  = t >> 5;                 // wave-uniform b' eighth
    const int r  = t & 31;
    const int ba = e * 64 + r;
    const int bb = ba + 32;

    __half2 A2[DK], B2[DK];
    #pragma unroll
    for (int d = 0; d < DK; ++d) {
        A2[d] = __half2half2(a16s[d * B + ba]);
        B2[d] = __half2half2(a16s[d * B + bb]);
    }
    const H2 ones = {__half2half2(__float2half(1.0f))};

    float accA = 0.f, accB = 0.f;
    const int bp0 = g * 64;

    union W8 { f16x8 v; __half2 h[4]; };
    #pragma unroll 2
    for (int m = 0; m < 8; ++m) {
        const int bp = bp0 + m * 8;
        W8 w0, w1, w2, w3, w4;
        w0.v = *(const f16x8*)&a16s[0*B + bp];
        w1.v = *(const f16x8*)&a16s[1*B + bp];
        w2.v = *(const f16x8*)&a16s[2*B + bp];
        w3.v = *(const f16x8*)&a16s[3*B + bp];
        w4.v = *(const f16x8*)&a16s[4*B + bp];
        #pragma unroll
        for (int c = 0; c < 4; ++c) {
            __half2 dA = __habs2(__hsub2(A2[0], w0.h[c]));
            dA = __hadd2(dA, __habs2(__hsub2(A2[1], w1.h[c])));
            dA = __hadd2(dA, __habs2(__hsub2(A2[2], w2.h[c])));
            dA = __hadd2(dA, __habs2(__hsub2(A2[3], w3.h[c])));
            dA = __hadd2(dA, __habs2(__hsub2(A2[4], w4.h[c])));
            H2 eA; eA.h = h2exp2(__hneg2(dA));
            __half2 dB = __habs2(__hsub2(B2[0], w0.h[c]));
            dB = __hadd2(dB, __habs2(__hsub2(B2[1], w1.h[c])));
            dB = __hadd2(dB, __habs2(__hsub2(B2[2], w2.h[c])));
            dB = __hadd2(dB, __habs2(__hsub2(B2[3], w3.h[c])));
            dB = __hadd2(dB, __habs2(__hsub2(B2[4], w4.h[c])));
            H2 eB; eB.h = h2exp2(__hneg2(dB));
#if __has_builtin(__builtin_amdgcn_fdot2)
            accA = __builtin_amdgcn_fdot2(eA.v, ones.v, accA, false);
            accB = __builtin_amdgcn_fdot2(eB.v, ones.v, accB, false);
#else
            accA += __low2float(eA.h) + __high2float(eA.h);
            accB += __low2float(eB.h) + __high2float(eB.h);
#endif
        }
    }
    red[g * 64 + r]      = accA;
    red[g * 64 + 32 + r] = accB;
    __syncthreads();
    if (t < 64) {
        float f = -1.0f + bias[k];
        #pragma unroll
        for (int gg = 0; gg < 8; ++gg) f += red[gg * 64 + t];
        out[(e * 64 + t) * NOUT + NIN + k] = f;
    }
}

// ---------------------------------------------------------------------------
extern "C" void kernel_launch(void* const* d_in, const int* in_sizes, int n_in,
                              void* d_out, int out_size, void* d_ws, size_t ws_size,
                              hipStream_t stream) {
    const float* x     = (const float*)d_in[0];   // [512,1024]
    const float* theta = (const float*)d_in[1];   // [1024,128,5]
    const float* lws   = (const float*)d_in[2];   // [128,5]
    const float* bias  = (const float*)d_in[3];   // [128]
    float* out = (float*)d_out;                   // [512,1152]

    // ws layout: ps @0 (64KB pad), actvP f32 8 slabs @64KB (10.49MB), actv16 after
    char* wsb = (char*)d_ws;
    float*  ps     = (float*)wsb;
    float*  actvP  = (float*)(wsb + (64 << 10));
    __half* actv16 = (__half*)(wsb + (64 << 10)
                               + (size_t)SPLITK * sizeof(float) * NF * B);

    gemm_kernel<<<dim3(640), 256, 0, stream>>>(x, theta, actvP, ps);
    rs_kernel<<<dim3(320), 256, 0, stream>>>(actvP, ps, lws, actv16);
    pairwise_kernel<<<dim3(NK, 8), 256, 0, stream>>>(actv16, bias, x, out);
}

// Round 9
// 24.818 us; speedup vs baseline: 1.1459x; 1.1459x over previous
//
#include <hip/hip_runtime.h>
#include <hip/hip_fp16.h>
#include <math.h>

constexpr int B    = 512;
constexpr int NIN  = 1024;
constexpr int NK   = 128;
constexpr int DK   = 5;
constexpr int NF   = NK * DK;     // 640 flattened kernel columns
constexpr int NOUT = NIN + NK;    // 1152
constexpr int SPLITK = 8;         // K chunks (128 each)
constexpr int LDA = 136;          // LDS row stride in halves (128 + 8 pad)
#define LOG2E 1.44269504088896f

typedef _Float16 f16x2 __attribute__((ext_vector_type(2)));
typedef _Float16 f16x4 __attribute__((ext_vector_type(4)));
typedef _Float16 f16x8 __attribute__((ext_vector_type(8)));
typedef float    f32x4 __attribute__((ext_vector_type(4)));

union H2 { __half2 h; f16x2 v; unsigned u; };

// ---------------------------------------------------------------------------
// Kernel 1: split-K MFMA GEMM, single staging phase, f16 partial output.
//   grid 640 = 80 tiles (10n x 8b) x 8 z; 256 thr = 4 waves.
//   actvP16[z][n][b] f16 partials; ps[z][n] theta^2 partials (b0==0 blocks).
// ---------------------------------------------------------------------------
__global__ __launch_bounds__(256) void gemm_kernel(
        const float* __restrict__ x,       // [512][1024]
        const float* __restrict__ theta,   // [1024][640]
        __half* __restrict__ actvP16,      // [8][640][512]
        float* __restrict__ ps) {          // [8][640]
    __shared__ _Float16 Ath[64 * LDA];     // theta^T tile [n][k]
    __shared__ _Float16 Bxh[64 * LDA];     // x tile [b][k]
    __shared__ float    red2[16][64];

    const int t    = threadIdx.x;
    const int tile = blockIdx.x >> 3;
    const int z    = blockIdx.x & 7;
    const int n0   = (tile >> 3) * 64;
    const int b0   = (tile & 7) * 64;
    const bool do_ps = (tile & 7) == 0;
    const int kw   = z * 128;

    // ---- stage theta: thread (kq = t>>4, 4 n-cols) reads 8 k-rows ----
    const int kq  = t >> 4;            // 0..15
    const int tn4 = (t & 15) * 4;
    float4 tv[8];
    #pragma unroll
    for (int i = 0; i < 8; ++i)
        tv[i] = *(const float4*)&theta[(kw + kq * 8 + i) * NF + n0 + tn4];

    // ---- stage x: thread (br = t>>2, ki = t&3) reads 8 float4 along k ----
    const int br = t >> 2;             // 0..63
    const int ki = t & 3;
    float4 xv[8];
    #pragma unroll
    for (int i = 0; i < 8; ++i)
        xv[i] = *(const float4*)&x[(b0 + br) * NIN + kw + (ki + i * 4) * 4];

    if (do_ps) {
        float sq0 = 0.f, sq1 = 0.f, sq2 = 0.f, sq3 = 0.f;
        #pragma unroll
        for (int i = 0; i < 8; ++i) {
            sq0 += tv[i].x * tv[i].x;  sq1 += tv[i].y * tv[i].y;
            sq2 += tv[i].z * tv[i].z;  sq3 += tv[i].w * tv[i].w;
        }
        red2[kq][tn4 + 0] = sq0;  red2[kq][tn4 + 1] = sq1;
        red2[kq][tn4 + 2] = sq2;  red2[kq][tn4 + 3] = sq3;
    }

    // transpose theta regs -> Ath[n][k]
    {
        f16x8 h;
        #pragma unroll
        for (int i = 0; i < 8; ++i) h[i] = (_Float16)tv[i].x;
        *(f16x8*)&Ath[(tn4 + 0) * LDA + kq * 8] = h;
        #pragma unroll
        for (int i = 0; i < 8; ++i) h[i] = (_Float16)tv[i].y;
        *(f16x8*)&Ath[(tn4 + 1) * LDA + kq * 8] = h;
        #pragma unroll
        for (int i = 0; i < 8; ++i) h[i] = (_Float16)tv[i].z;
        *(f16x8*)&Ath[(tn4 + 2) * LDA + kq * 8] = h;
        #pragma unroll
        for (int i = 0; i < 8; ++i) h[i] = (_Float16)tv[i].w;
        *(f16x8*)&Ath[(tn4 + 3) * LDA + kq * 8] = h;
    }
    // x regs -> Bxh[b][k]
    #pragma unroll
    for (int i = 0; i < 8; ++i) {
        f16x4 h;
        h[0] = (_Float16)xv[i].x;  h[1] = (_Float16)xv[i].y;
        h[2] = (_Float16)xv[i].z;  h[3] = (_Float16)xv[i].w;
        *(f16x4*)&Bxh[br * LDA + (ki + i * 4) * 4] = h;
    }
    __syncthreads();

    // ---- MFMA: wave w owns n-sub w*16; 4 b-subtiles x 4 k-steps ----
    const int w   = t >> 6;
    const int l   = t & 63;
    const int r16 = l & 15;
    const int kg  = l >> 4;

    f32x4 acc0 = {0.f,0.f,0.f,0.f}, acc1 = {0.f,0.f,0.f,0.f};
    f32x4 acc2 = {0.f,0.f,0.f,0.f}, acc3 = {0.f,0.f,0.f,0.f};
    #pragma unroll
    for (int ks = 0; ks < 4; ++ks) {
        const f16x8 av  = *(const f16x8*)&Ath[(w*16 + r16)*LDA + ks*32 + kg*8];
        const f16x8 bv0 = *(const f16x8*)&Bxh[( 0 + r16)*LDA + ks*32 + kg*8];
        const f16x8 bv1 = *(const f16x8*)&Bxh[(16 + r16)*LDA + ks*32 + kg*8];
        const f16x8 bv2 = *(const f16x8*)&Bxh[(32 + r16)*LDA + ks*32 + kg*8];
        const f16x8 bv3 = *(const f16x8*)&Bxh[(48 + r16)*LDA + ks*32 + kg*8];
        acc0 = __builtin_amdgcn_mfma_f32_16x16x32_f16(av, bv0, acc0, 0, 0, 0);
        acc1 = __builtin_amdgcn_mfma_f32_16x16x32_f16(av, bv1, acc1, 0, 0, 0);
        acc2 = __builtin_amdgcn_mfma_f32_16x16x32_f16(av, bv2, acc2, 0, 0, 0);
        acc3 = __builtin_amdgcn_mfma_f32_16x16x32_f16(av, bv3, acc3, 0, 0, 0);
    }

    // store f16 partials: C map col=lane&15, row=(lane>>4)*4+reg [m89/m91]
    {
        __half* dst = actvP16 + (size_t)z * NF * B
                    + (size_t)(n0 + w*16 + kg*4) * B + b0 + r16;
        #pragma unroll
        for (int j = 0; j < 4; ++j) {
            dst[j*B +  0] = __float2half(acc0[j]);
            dst[j*B + 16] = __float2half(acc1[j]);
            dst[j*B + 32] = __float2half(acc2[j]);
            dst[j*B + 48] = __float2half(acc3[j]);
        }
    }
    if (do_ps) {
        __syncthreads();
        if (t < 64) {
            float tot = 0.f;
            #pragma unroll
            for (int rr = 0; rr < 16; ++rr) tot += red2[rr][t];
            ps[z * NF + n0 + t] = tot;
        }
    }
}

// ---------------------------------------------------------------------------
// Kernel 2: pairwise finish with integrated split-K reduce + scale.
//   a16s[d,b] = f16( s_d * sum_z actvP16[z][k*5+d][b] ),
//   s_d = exp(lws)*rsqrt(sum_z ps)*log2e
//   f[b,k] = sum_{b'} exp2(-sum_d |a16s[d,b]-a16s[d,b']|) - 1 + bias[k]
// grid (128 k, 8 e) = 1024 blocks, 256 thr (4 blocks/CU).
// ---------------------------------------------------------------------------
__global__ __launch_bounds__(256) void pairwise_kernel(
        const __half* __restrict__ actvP16,// [8][640][512]
        const float* __restrict__ ps,      // [8][640]
        const float* __restrict__ lws,     // [640]
        const float* __restrict__ bias,    // [128]
        const float* __restrict__ x,       // [512][1024]
        float* __restrict__ out) {         // [512][1152]
    __shared__ __half a16s[DK * B];        // 5120 B
    __shared__ float  red[8 * 64];
    __shared__ float  s_sh[DK];
    __shared__ float  red_ps[DK * SPLITK];

    const int k = blockIdx.x;
    const int e = blockIdx.y;
    const int t = threadIdx.x;

    // fused x passthrough: 4 of the 8 blocks per k copy one row each
    if (e < 4) {
        const int row = k * 4 + e;
        ((float4*)out)[row * (NOUT/4) + t] = ((const float4*)x)[row * (NIN/4) + t];
    }

    if (t < DK * SPLITK)
        red_ps[t] = ps[(t / DK) * NF + k * DK + (t % DK)];

    // ---- split-K reduce into f32 regs: unit u = 8 halves of the k-slab ----
    // units 0..319; thread t does unit t, threads t<64 also unit 256+t.
    const size_t slab = (size_t)k * DK * B;
    float acc0f[8], acc1f[8];
    {
        #pragma unroll
        for (int i = 0; i < 8; ++i) { acc0f[i] = 0.f; acc1f[i] = 0.f; }
        #pragma unroll
        for (int z = 0; z < SPLITK; ++z) {
            const f16x8 v = *(const f16x8*)(actvP16 + (size_t)z * NF * B + slab + t * 8);
            #pragma unroll
            for (int i = 0; i < 8; ++i) acc0f[i] += (float)v[i];
        }
        if (t < 64) {
            #pragma unroll
            for (int z = 0; z < SPLITK; ++z) {
                const f16x8 v = *(const f16x8*)(actvP16 + (size_t)z * NF * B + slab + 2048 + t * 8);
                #pragma unroll
                for (int i = 0; i < 8; ++i) acc1f[i] += (float)v[i];
            }
        }
    }
    __syncthreads();
    if (t < DK) {
        float sum = 0.f;
        #pragma unroll
        for (int c = 0; c < SPLITK; ++c) sum += red_ps[c * DK + t];
        s_sh[t] = __expf(lws[k * DK + t]) * rsqrtf(sum) * LOG2E;
    }
    __syncthreads();
    {
        const float s0 = s_sh[t >> 6];     // d = unit/64, wave-uniform
        f16x8 h;
        #pragma unroll
        for (int i = 0; i < 8; ++i) h[i] = (_Float16)(acc0f[i] * s0);
        *(f16x8*)&a16s[t * 8] = h;
        if (t < 64) {
            const float s1 = s_sh[4];      // units 256..319 are d=4
            #pragma unroll
            for (int i = 0; i < 8; ++i) h[i] = (_Float16)(acc1f[i] * s1);
            *(f16x8*)&a16s[2048 + t * 8] = h;
        }
    }
    __syncthreads();

    const int g  = t >> 5;                 // wave-uniform b' eighth
    const int r  = t & 31;
    const int ba = e * 64 + r;
    const int bb = ba + 32;

    __half2 A2[DK], B2[DK];
    #pragma unroll
    for (int d = 0; d < DK; ++d) {
        A2[d] = __half2half2(a16s[d * B + ba]);
        B2[d] = __half2half2(a16s[d * B + bb]);
    }
    const H2 ones = {__half2half2(__float2half(1.0f))};

    float accA = 0.f, accB = 0.f;
    const int bp0 = g * 64;

    union W8 { f16x8 v; __half2 h[4]; };
    #pragma unroll 2
    for (int m = 0; m < 8; ++m) {
        const int bp = bp0 + m * 8;        // wave-uniform -> LDS b128 broadcast
        W8 w0, w1, w2, w3, w4;
        w0.v = *(const f16x8*)&a16s[0*B + bp];
        w1.v = *(const f16x8*)&a16s[1*B + bp];
        w2.v = *(const f16x8*)&a16s[2*B + bp];
        w3.v = *(const f16x8*)&a16s[3*B + bp];
        w4.v = *(const f16x8*)&a16s[4*B + bp];
        #pragma unroll
        for (int c = 0; c < 4; ++c) {
            __half2 dA = __habs2(__hsub2(A2[0], w0.h[c]));
            dA = __hadd2(dA, __habs2(__hsub2(A2[1], w1.h[c])));
            dA = __hadd2(dA, __habs2(__hsub2(A2[2], w2.h[c])));
            dA = __hadd2(dA, __habs2(__hsub2(A2[3], w3.h[c])));
            dA = __hadd2(dA, __habs2(__hsub2(A2[4], w4.h[c])));
            H2 eA; eA.h = h2exp2(__hneg2(dA));
            __half2 dB = __habs2(__hsub2(B2[0], w0.h[c]));
            dB = __hadd2(dB, __habs2(__hsub2(B2[1], w1.h[c])));
            dB = __hadd2(dB, __habs2(__hsub2(B2[2], w2.h[c])));
            dB = __hadd2(dB, __habs2(__hsub2(B2[3], w3.h[c])));
            dB = __hadd2(dB, __habs2(__hsub2(B2[4], w4.h[c])));
            H2 eB; eB.h = h2exp2(__hneg2(dB));
#if __has_builtin(__builtin_amdgcn_fdot2)
            accA = __builtin_amdgcn_fdot2(eA.v, ones.v, accA, false);
            accB = __builtin_amdgcn_fdot2(eB.v, ones.v, accB, false);
#else
            accA += __low2float(eA.h) + __high2float(eA.h);
            accB += __low2float(eB.h) + __high2float(eB.h);
#endif
        }
    }
    red[g * 64 + r]      = accA;
    red[g * 64 + 32 + r] = accB;
    __syncthreads();
    if (t < 64) {
        float f = -1.0f + bias[k];
        #pragma unroll
        for (int gg = 0; gg < 8; ++gg) f += red[gg * 64 + t];
        out[(e * 64 + t) * NOUT + NIN + k] = f;
    }
}

// ---------------------------------------------------------------------------
extern "C" void kernel_launch(void* const* d_in, const int* in_sizes, int n_in,
                              void* d_out, int out_size, void* d_ws, size_t ws_size,
                              hipStream_t stream) {
    const float* x     = (const float*)d_in[0];   // [512,1024]
    const float* theta = (const float*)d_in[1];   // [1024,128,5]
    const float* lws   = (const float*)d_in[2];   // [128,5]
    const float* bias  = (const float*)d_in[3];   // [128]
    float* out = (float*)d_out;                   // [512,1152]

    // ws layout: ps @0 (64KB pad), actvP16 f16 8 slabs @64KB (5.24MB)
    char* wsb = (char*)d_ws;
    float*  ps       = (float*)wsb;
    __half* actvP16  = (__half*)(wsb + (64 << 10));

    gemm_kernel<<<dim3(640), 256, 0, stream>>>(x, theta, actvP16, ps);
    pairwise_kernel<<<dim3(NK, 8), 256, 0, stream>>>(actvP16, ps, lws, bias, x, out);
}

// Round 10
// 23.996 us; speedup vs baseline: 1.1851x; 1.0343x over previous
//
#include <hip/hip_runtime.h>
#include <hip/hip_fp16.h>
#include <math.h>

constexpr int B    = 512;
constexpr int NIN  = 1024;
constexpr int NK   = 128;
constexpr int DK   = 5;
constexpr int NF   = NK * DK;     // 640 flattened kernel columns
constexpr int NOUT = NIN + NK;    // 1152
constexpr int SPLITK = 8;         // K chunks (128 each)
constexpr int LDA = 136;          // LDS row stride in halves (128 + 8 pad)
#define LOG2E 1.44269504088896f

typedef _Float16 f16x4 __attribute__((ext_vector_type(4)));
typedef _Float16 f16x8 __attribute__((ext_vector_type(8)));
typedef float    f32x4 __attribute__((ext_vector_type(4)));

union H2 { __half2 h; unsigned u; };

// ---------------------------------------------------------------------------
// Kernel 1: split-K MFMA GEMM, 32n x 64b x 128k tiles, f16 partial output.
//   grid 1280 = (20 n-tiles x 8 b-tiles) x 8 z; 256 thr = 4 waves.
//   5 blocks/CU co-resident (LDS ~30KB) -> ~5 waves/SIMD latency hiding.
// ---------------------------------------------------------------------------
__global__ __launch_bounds__(256) void gemm_kernel(
        const float* __restrict__ x,       // [512][1024]
        const float* __restrict__ theta,   // [1024][640]
        __half* __restrict__ actvP16,      // [8][640][512]
        float* __restrict__ ps) {          // [8][640]
    __shared__ _Float16 Ath[32 * LDA];     // theta^T tile [n][k]
    __shared__ _Float16 Bxh[64 * LDA];     // x tile [b][k]
    __shared__ float    red2[32][33];

    const int t    = threadIdx.x;
    const int tile = blockIdx.x >> 3;
    const int z    = blockIdx.x & 7;
    const int nt   = tile >> 3;            // 0..19
    const int bt   = tile & 7;             // 0..7
    const int n0   = nt * 32;
    const int b0   = bt * 64;
    const bool do_ps = (bt == 0);
    const int kw   = z * 128;

    // ---- stage theta: thread (kq = t>>3, nc = (t&7)*4) reads 4 k-rows ----
    const int kq = t >> 3;                 // 0..31, k-rows kq*4..+3
    const int nc = (t & 7) * 4;            // 4 n-cols
    float4 tv0 = *(const float4*)&theta[(kw + kq*4 + 0) * NF + n0 + nc];
    float4 tv1 = *(const float4*)&theta[(kw + kq*4 + 1) * NF + n0 + nc];
    float4 tv2 = *(const float4*)&theta[(kw + kq*4 + 2) * NF + n0 + nc];
    float4 tv3 = *(const float4*)&theta[(kw + kq*4 + 3) * NF + n0 + nc];

    // ---- stage x: thread (br = t>>2, ki = t&3) reads 8 float4 along k ----
    const int br = t >> 2;                 // 0..63
    const int ki = t & 3;
    float4 xv[8];
    #pragma unroll
    for (int i = 0; i < 8; ++i)
        xv[i] = *(const float4*)&x[(b0 + br) * NIN + kw + (ki + i * 4) * 4];

    if (do_ps) {
        red2[kq][nc + 0] = tv0.x*tv0.x + tv1.x*tv1.x + tv2.x*tv2.x + tv3.x*tv3.x;
        red2[kq][nc + 1] = tv0.y*tv0.y + tv1.y*tv1.y + tv2.y*tv2.y + tv3.y*tv3.y;
        red2[kq][nc + 2] = tv0.z*tv0.z + tv1.z*tv1.z + tv2.z*tv2.z + tv3.z*tv3.z;
        red2[kq][nc + 3] = tv0.w*tv0.w + tv1.w*tv1.w + tv2.w*tv2.w + tv3.w*tv3.w;
    }

    // transpose theta regs -> Ath[n][k] (f16x4 along k)
    {
        f16x4 h;
        h[0]=(_Float16)tv0.x; h[1]=(_Float16)tv1.x; h[2]=(_Float16)tv2.x; h[3]=(_Float16)tv3.x;
        *(f16x4*)&Ath[(nc + 0) * LDA + kq * 4] = h;
        h[0]=(_Float16)tv0.y; h[1]=(_Float16)tv1.y; h[2]=(_Float16)tv2.y; h[3]=(_Float16)tv3.y;
        *(f16x4*)&Ath[(nc + 1) * LDA + kq * 4] = h;
        h[0]=(_Float16)tv0.z; h[1]=(_Float16)tv1.z; h[2]=(_Float16)tv2.z; h[3]=(_Float16)tv3.z;
        *(f16x4*)&Ath[(nc + 2) * LDA + kq * 4] = h;
        h[0]=(_Float16)tv0.w; h[1]=(_Float16)tv1.w; h[2]=(_Float16)tv2.w; h[3]=(_Float16)tv3.w;
        *(f16x4*)&Ath[(nc + 3) * LDA + kq * 4] = h;
    }
    // x regs -> Bxh[b][k]
    #pragma unroll
    for (int i = 0; i < 8; ++i) {
        f16x4 h;
        h[0] = (_Float16)xv[i].x;  h[1] = (_Float16)xv[i].y;
        h[2] = (_Float16)xv[i].z;  h[3] = (_Float16)xv[i].w;
        *(f16x4*)&Bxh[br * LDA + (ki + i * 4) * 4] = h;
    }
    __syncthreads();

    // ---- MFMA: wave w owns b-sub w*16; 2 n-subs x 4 k-steps = 8 MFMA ----
    const int w   = t >> 6;
    const int l   = t & 63;
    const int r16 = l & 15;
    const int kg  = l >> 4;

    f32x4 acc0 = {0.f,0.f,0.f,0.f}, acc1 = {0.f,0.f,0.f,0.f};
    #pragma unroll
    for (int ks = 0; ks < 4; ++ks) {
        const f16x8 bv  = *(const f16x8*)&Bxh[(w*16 + r16)*LDA + ks*32 + kg*8];
        const f16x8 av0 = *(const f16x8*)&Ath[( 0 + r16)*LDA + ks*32 + kg*8];
        const f16x8 av1 = *(const f16x8*)&Ath[(16 + r16)*LDA + ks*32 + kg*8];
        acc0 = __builtin_amdgcn_mfma_f32_16x16x32_f16(av0, bv, acc0, 0, 0, 0);
        acc1 = __builtin_amdgcn_mfma_f32_16x16x32_f16(av1, bv, acc1, 0, 0, 0);
    }

    // store f16 partials: C map col(b)=lane&15, row(n)=(lane>>4)*4+reg [m89/m91]
    {
        __half* dst = actvP16 + (size_t)z * NF * B
                    + (size_t)(n0 + kg*4) * B + b0 + w*16 + r16;
        #pragma unroll
        for (int j = 0; j < 4; ++j) {
            dst[j*B]          = __float2half(acc0[j]);
            dst[(16 + j) * B] = __float2half(acc1[j]);
        }
    }
    if (do_ps) {
        __syncthreads();
        if (t < 32) {
            float tot = 0.f;
            #pragma unroll
            for (int rr = 0; rr < 32; ++rr) tot += red2[rr][t];
            ps[z * NF + n0 + t] = tot;
        }
    }
}

// ---------------------------------------------------------------------------
// Kernel 2: pairwise finish with integrated split-K reduce + scale.
// grid (128 k, 4 e) x 512 thr (2 blocks/CU, 16 waves/CU).
//   waves 0-4: slab reduce; waves 4-7: x-row copy; wave 7: ps loads.
//   f[b,k] = sum_{b'} exp2(-sum_d |a16s[d,b]-a16s[d,b']|) - 1 + bias[k]
// ---------------------------------------------------------------------------
__global__ __launch_bounds__(512) void pairwise_kernel(
        const __half* __restrict__ actvP16,// [8][640][512]
        const float* __restrict__ ps,      // [8][640]
        const float* __restrict__ lws,     // [640]
        const float* __restrict__ bias,    // [128]
        const float* __restrict__ x,       // [512][1024]
        float* __restrict__ out) {         // [512][1152]
    __shared__ __half a16s[DK * B];        // 5120 B
    __shared__ float  red[8 * 128];
    __shared__ float  s_sh[DK];
    __shared__ float  red_ps[DK * SPLITK];

    const int k = blockIdx.x;
    const int e = blockIdx.y;              // b-quarter (0..3)
    const int t = threadIdx.x;

    // fused x passthrough: upper half threads copy row k*4+e
    if (t >= 256) {
        const int u = t - 256;
        const int row = k * 4 + e;
        ((float4*)out)[row * (NOUT/4) + u] = ((const float4*)x)[row * (NIN/4) + u];
    }
    if (t >= 448 && t < 448 + DK * SPLITK) {
        const int u = t - 448;
        red_ps[u] = ps[(u / DK) * NF + k * DK + (u % DK)];
    }

    // ---- split-K reduce into f32 regs: unit t = 8 halves (t < 320) ----
    const size_t slab = (size_t)k * DK * B;
    float accf[8];
    #pragma unroll
    for (int i = 0; i < 8; ++i) accf[i] = 0.f;
    if (t < 320) {
        #pragma unroll
        for (int z = 0; z < SPLITK; ++z) {
            const f16x8 v = *(const f16x8*)(actvP16 + (size_t)z * NF * B + slab + t * 8);
            #pragma unroll
            for (int i = 0; i < 8; ++i) accf[i] += (float)v[i];
        }
    }
    __syncthreads();
    if (t < DK) {
        float sum = 0.f;
        #pragma unroll
        for (int c = 0; c < SPLITK; ++c) sum += red_ps[c * DK + t];
        s_sh[t] = __expf(lws[k * DK + t]) * rsqrtf(sum) * LOG2E;
    }
    __syncthreads();
    if (t < 320) {
        const float s = s_sh[t >> 6];      // d = t/64, wave-uniform
        f16x8 h;
        #pragma unroll
        for (int i = 0; i < 8; ++i) h[i] = (_Float16)(accf[i] * s);
        *(f16x8*)&a16s[t * 8] = h;
    }
    __syncthreads();

    const int g  = t >> 6;                 // wave-uniform b' eighth (0..7)
    const int r  = t & 63;
    const int ba = e * 128 + r;
    const int bb = ba + 64;

    __half2 A2[DK], B2[DK];
    #pragma unroll
    for (int d = 0; d < DK; ++d) {
        A2[d] = __half2half2(a16s[d * B + ba]);
        B2[d] = __half2half2(a16s[d * B + bb]);
    }

    float accA = 0.f, accB = 0.f;
    const int bp0 = g * 64;

    union W8 { f16x8 v; __half2 h[4]; };
    typedef _Float16 f16x2v __attribute__((ext_vector_type(2)));
    union HV { __half2 h; f16x2v v; };
    const HV ones = {__half2half2(__float2half(1.0f))};

    #pragma unroll 2
    for (int m = 0; m < 8; ++m) {
        const int bp = bp0 + m * 8;        // wave-uniform -> LDS b128 broadcast
        W8 w0, w1, w2, w3, w4;
        w0.v = *(const f16x8*)&a16s[0*B + bp];
        w1.v = *(const f16x8*)&a16s[1*B + bp];
        w2.v = *(const f16x8*)&a16s[2*B + bp];
        w3.v = *(const f16x8*)&a16s[3*B + bp];
        w4.v = *(const f16x8*)&a16s[4*B + bp];
        #pragma unroll
        for (int c = 0; c < 4; ++c) {
            __half2 dA = __habs2(__hsub2(A2[0], w0.h[c]));
            dA = __hadd2(dA, __habs2(__hsub2(A2[1], w1.h[c])));
            dA = __hadd2(dA, __habs2(__hsub2(A2[2], w2.h[c])));
            dA = __hadd2(dA, __habs2(__hsub2(A2[3], w3.h[c])));
            dA = __hadd2(dA, __habs2(__hsub2(A2[4], w4.h[c])));
            HV eA; eA.h = h2exp2(__hneg2(dA));
            __half2 dB = __habs2(__hsub2(B2[0], w0.h[c]));
            dB = __hadd2(dB, __habs2(__hsub2(B2[1], w1.h[c])));
            dB = __hadd2(dB, __habs2(__hsub2(B2[2], w2.h[c])));
            dB = __hadd2(dB, __habs2(__hsub2(B2[3], w3.h[c])));
            dB = __hadd2(dB, __habs2(__hsub2(B2[4], w4.h[c])));
            HV eB; eB.h = h2exp2(__hneg2(dB));
#if __has_builtin(__builtin_amdgcn_fdot2)
            accA = __builtin_amdgcn_fdot2(eA.v, ones.v, accA, false);
            accB = __builtin_amdgcn_fdot2(eB.v, ones.v, accB, false);
#else
            accA += __low2float(eA.h) + __high2float(eA.h);
            accB += __low2float(eB.h) + __high2float(eB.h);
#endif
        }
    }
    red[g * 128 + r]      = accA;
    red[g * 128 + 64 + r] = accB;
    __syncthreads();
    if (t < 128) {
        float f = -1.0f + bias[k];
        #pragma unroll
        for (int gg = 0; gg < 8; ++gg) f += red[gg * 128 + t];
        out[(e * 128 + t) * NOUT + NIN + k] = f;
    }
}

// ---------------------------------------------------------------------------
extern "C" void kernel_launch(void* const* d_in, const int* in_sizes, int n_in,
                              void* d_out, int out_size, void* d_ws, size_t ws_size,
                              hipStream_t stream) {
    const float* x     = (const float*)d_in[0];   // [512,1024]
    const float* theta = (const float*)d_in[1];   // [1024,128,5]
    const float* lws   = (const float*)d_in[2];   // [128,5]
    const float* bias  = (const float*)d_in[3];   // [128]
    float* out = (float*)d_out;                   // [512,1152]

    // ws layout: ps @0 (64KB pad), actvP16 f16 8 slabs @64KB (5.24MB)
    char* wsb = (char*)d_ws;
    float*  ps       = (float*)wsb;
    __half* actvP16  = (__half*)(wsb + (64 << 10));

    gemm_kernel<<<dim3(1280), 256, 0, stream>>>(x, theta, actvP16, ps);
    pairwise_kernel<<<dim3(NK, 4), 512, 0, stream>>>(actvP16, ps, lws, bias, x, out);
}